// Round 9
// baseline (271.021 us; speedup 1.0000x reference)
//
#include <hip/hip_runtime.h>

// Seq2SeqLSTM: H=64, F=8, T=512, P=64, B=1024, fp32 in/out.
// R9: x-MFMAs amortized over 4-step groups. xs A-rows m=4b+s -> one MFMA per
// gate yields x-contrib for 4 steps (D row 4q+r = batch q, step r); per-step
// x-MFMA pipe cost drops 64->16 cyc. Double-buffered Pw register sets (Pw for
// group g+1 computed mid-group g from an x-load issued 2 steps earlier).
// Serial-path folds: tg2=fma(rcp,-2K,K); hn=fma(rcp,-2so,so).
// Base structure (R7/R8): MB=4 over 256 blocks; lane (q,col) owns cell
// (batch q, unit wv*16+col); batch b at A-row 4b so C/D row=4q+0 puts the
// lane's gates in acc[.][0]; fp16 weights/h/x pre-scaled by log2e (2x for g).

#define Hh 64
#define Ff 8
#define Tt 512
#define Pp 64
#define BATCH 1024
#define MB 4
#define NBLK (BATCH / MB)   // 256 blocks
#define ROWS 72             // halves per A row (64 + 8 pad)
#define ABUF (16 * ROWS + 64)
#define XSTRIDE 32          // halves per x step-row: 4 batches * 8

typedef __attribute__((ext_vector_type(8))) _Float16 half8;
typedef __attribute__((ext_vector_type(4))) _Float16 half4;
typedef __attribute__((ext_vector_type(4))) float f32x4;

#define LOG2E  1.44269504088896340736f
#define K2LOG2 2.88538008177792681472f   // 2*log2e

__device__ __forceinline__ float rcp_(float x)  { return __builtin_amdgcn_rcpf(x); }
__device__ __forceinline__ float exp2_(float x) { return __builtin_amdgcn_exp2f(x); }
// A-row swizzle (halves): rows 4b (writers) keep offset 0.
__device__ __forceinline__ int arow_base(int m) { return m * ROWS + (m & 3) * 16; }

// B-fragments: 4 gate tiles, fp16, log2e-pre-scaled (2*log2e for g-gate).
// B layout (16x16x32): lane holds B[k = kc*32 + q*8 + j][n = col].
// wx rows k>=8 are ZERO for q>=1 lanes -> garbage A rows k>=8 are harmless.
__device__ __forceinline__ void load_wfrags(
    const float* __restrict__ Whh, const float* __restrict__ Wih,
    int wv, int q, int col, half8 w0[4], half8 w1[4], half8 wx[4])
{
    #pragma unroll
    for (int Tg = 0; Tg < 4; ++Tg) {
        int g = Tg * 64 + wv * 16 + col;
        float sc = (Tg == 2) ? K2LOG2 : LOG2E;
        const float* r0 = Whh + g * 64 + q * 8;
        #pragma unroll
        for (int j = 0; j < 8; ++j) {
            w0[Tg][j] = (_Float16)(r0[j] * sc);
            w1[Tg][j] = (_Float16)(r0[32 + j] * sc);
            wx[Tg][j] = (q == 0) ? (_Float16)(Wih[g * 8 + j] * sc) : (_Float16)0.f;
        }
    }
}

// Group P: one MFMA per gate computes bias + x*Wih^T for FOUR steps.
// A rows m = 4b+s (lane supplies A[m=col][k=q*8+j] = x[b=col>>2][t0+(col&3)][j];
// rows with k>=8 are garbage, killed by zero wx rows). D[r] of lane (q,col)
// = (batch q, step r, gate-col col).
__device__ __forceinline__ void pgroup(half8 axg, const half8 wx[4],
                                       const f32x4 biasv[4], f32x4 Pw[4])
{
    Pw[2] = __builtin_amdgcn_mfma_f32_16x16x32_f16(axg, wx[2], biasv[2], 0, 0, 0);
    Pw[0] = __builtin_amdgcn_mfma_f32_16x16x32_f16(axg, wx[0], biasv[0], 0, 0, 0);
    Pw[1] = __builtin_amdgcn_mfma_f32_16x16x32_f16(axg, wx[1], biasv[1], 0, 0, 0);
    Pw[3] = __builtin_amdgcn_mfma_f32_16x16x32_f16(axg, wx[3], biasv[3], 0, 0, 0);
}

// Critical path: 8 MFMA (4 chains depth 2, gate order g,i,f,o) + cell update.
__device__ __forceinline__ float qcell(half8 a0, half8 a1,
    const half8 w0[4], const half8 w1[4],
    f32x4 Cg, f32x4 Ci, f32x4 Cf, f32x4 Co, float& cS)
{
    f32x4 Qg = __builtin_amdgcn_mfma_f32_16x16x32_f16(a0, w0[2], Cg, 0, 0, 0);
    f32x4 Qi = __builtin_amdgcn_mfma_f32_16x16x32_f16(a0, w0[0], Ci, 0, 0, 0);
    f32x4 Qf = __builtin_amdgcn_mfma_f32_16x16x32_f16(a0, w0[1], Cf, 0, 0, 0);
    f32x4 Qo = __builtin_amdgcn_mfma_f32_16x16x32_f16(a0, w0[3], Co, 0, 0, 0);
    Qg = __builtin_amdgcn_mfma_f32_16x16x32_f16(a1, w1[2], Qg, 0, 0, 0);
    Qi = __builtin_amdgcn_mfma_f32_16x16x32_f16(a1, w1[0], Qi, 0, 0, 0);
    Qf = __builtin_amdgcn_mfma_f32_16x16x32_f16(a1, w1[1], Qf, 0, 0, 0);
    Qo = __builtin_amdgcn_mfma_f32_16x16x32_f16(a1, w1[3], Qo, 0, 0, 0);
    float rg  = rcp_(1.f + exp2_(Qg[0]));
    float tg2 = __builtin_fmaf(rg, -2.f * K2LOG2, K2LOG2);   // K2LOG2 * tanh(g)
    float si  = rcp_(1.f + exp2_(-Qi[0]));
    float sf  = rcp_(1.f + exp2_(-Qf[0]));
    float so  = rcp_(1.f + exp2_(-Qo[0]));
    cS = __builtin_fmaf(sf, cS, si * tg2);
    float rc = rcp_(1.f + exp2_(cS));
    return __builtin_fmaf(rc, -2.f * so, so);                // so * tanh(c)
}

#define QSTEP(RD, WR, PW, R)                                                    \
    {                                                                           \
        half8 a0 = *(const half8*)(RD);                                         \
        half8 a1 = *(const half8*)(RD + 32);                                    \
        float hn = qcell(a0, a1, w0, w1,                                        \
            __builtin_shufflevector(PW[2], PW[2], R, R, R, R),                  \
            __builtin_shufflevector(PW[0], PW[0], R, R, R, R),                  \
            __builtin_shufflevector(PW[1], PW[1], R, R, R, R),                  \
            __builtin_shufflevector(PW[3], PW[3], R, R, R, R), cS);             \
        *(WR) = (_Float16)hn;                                                   \
    }

__global__ __launch_bounds__(256, 1)
void seq2seq_v9(const float* __restrict__ x_seq,
                const float* __restrict__ eWih, const float* __restrict__ eWhh,
                const float* __restrict__ ebih, const float* __restrict__ ebhh,
                const float* __restrict__ dWih, const float* __restrict__ dWhh,
                const float* __restrict__ dbih, const float* __restrict__ dbhh,
                const float* __restrict__ fcW,  const float* __restrict__ fcb,
                float* __restrict__ out)
{
    __shared__ __align__(16) _Float16 xs[(Tt + 8) * XSTRIDE];  // 33.3 KB; predbuf alias
    __shared__ __align__(16) _Float16 A0[ABUF];
    __shared__ __align__(16) _Float16 A1[ABUF];
    __shared__ float fcWT[Hh * 9 + 8];
    __shared__ float sfcb[Ff];
    __shared__ __align__(16) _Float16 xdec[MB * Ff];

    const int tid  = threadIdx.x;
    const int wv   = tid >> 6;
    const int lane = tid & 63;
    const int q    = lane >> 4;
    const int col  = lane & 15;
    const int u    = wv * 16 + col;
    const int b0   = blockIdx.x * MB;

    half8 w0[4], w1[4], wx[4];
    load_wfrags(eWhh, eWih, wv, q, col, w0, w1, wx);
    f32x4 biasv[4];
    #pragma unroll
    for (int Tg = 0; Tg < 4; ++Tg) {
        int g = Tg * 64 + u;
        float sc = (Tg == 2) ? K2LOG2 : LOG2E;
        float bv = (ebih[g] + ebhh[g]) * sc;
        biasv[Tg] = (f32x4){bv, bv, bv, bv};
    }

    // init: zero A buffers + xs pad rows, stage fc weights + x (fp32 -> fp16)
    { int* Z0 = (int*)A0; int* Z1 = (int*)A1;
      for (int i = tid; i < ABUF / 2; i += 256) { Z0[i] = 0; Z1[i] = 0; } }
    for (int i = tid; i < Ff * Hh; i += 256) { int f = i >> 6, uu = i & 63; fcWT[uu * 9 + f] = fcW[i]; }
    if (tid < Ff) sfcb[tid] = fcb[tid];
    if (tid < 128) ((int*)xs)[Tt * 16 + tid] = 0;        // zero 8 pad step-rows
    for (int i = tid; i < MB * Tt * 2; i += 256) {       // 4096 float4s
        int b   = i >> 10;
        int rem = i & 1023;
        int t   = rem >> 1;
        int f4  = (rem & 1) * 4;
        const float* src = x_seq + ((size_t)(b0 + b) * Tt + t) * Ff + f4;
        half4 s = { (_Float16)src[0], (_Float16)src[1], (_Float16)src[2], (_Float16)src[3] };
        *(half4*)(&xs[t * XSTRIDE + b * 8 + f4]) = s;
    }
    __syncthreads();                                     // staging visible

    // per-lane hoisted pointers
    const _Float16* arA = A0 + arow_base(col) + q * 8;
    const _Float16* arB = A1 + arow_base(col) + q * 8;
    _Float16* hwA = A0 + 4 * q * ROWS + u;
    _Float16* hwB = A1 + 4 * q * ROWS + u;
    // group-x walker: lane supplies A[m=col] = x[b=col>>2][t0 + (col&3)]
    const _Float16* xgp = xs + (col & 3) * XSTRIDE + (col >> 2) * 8;

    float cS = 0.f;
    f32x4 PwA[4], PwB[4];
    half8 axA, axB;
    {   half8 ax0 = *(const half8*)(xgp); xgp += 4 * XSTRIDE;   // group 0
        pgroup(ax0, wx, biasv, PwA);
        axB = *(const half8*)(xgp); xgp += 4 * XSTRIDE;         // group 1
    }

    // ============ encoder: 64 iters x 8 steps (2 groups), 1 barrier/step ============
    for (int it = 0; it < Tt / 8; ++it) {
        // ---- group 2it (PwA)
        __syncthreads(); QSTEP(arA, hwB, PwA, 0);
        __syncthreads(); QSTEP(arB, hwA, PwA, 1);
        __syncthreads(); pgroup(axB, wx, biasv, PwB);           // P(group 2it+1)
                         QSTEP(arA, hwB, PwA, 2);
        __syncthreads(); axA = *(const half8*)(xgp); xgp += 4 * XSTRIDE;  // x(group 2it+2)
                         QSTEP(arB, hwA, PwA, 3);
        // ---- group 2it+1 (PwB)
        __syncthreads(); QSTEP(arA, hwB, PwB, 0);
        __syncthreads(); QSTEP(arB, hwA, PwB, 1);
        __syncthreads(); pgroup(axA, wx, biasv, PwA);           // P(group 2it+2)
                         QSTEP(arA, hwB, PwB, 2);
        __syncthreads(); axB = *(const half8*)(xgp); xgp += 4 * XSTRIDE;  // x(group 2it+3)
                         QSTEP(arB, hwA, PwB, 3);
    }
    // after loop: h(512) in A0.

    // ================= decoder setup =================
    load_wfrags(dWhh, dWih, wv, q, col, w0, w1, wx);
    #pragma unroll
    for (int Tg = 0; Tg < 4; ++Tg) {
        int g = Tg * 64 + u;
        float sc = (Tg == 2) ? K2LOG2 : LOG2E;
        float bv = (dbih[g] + dbhh[g]) * sc;
        biasv[Tg] = (f32x4){bv, bv, bv, bv};
    }
    if (tid < MB * Ff) xdec[tid] = xs[(Tt - 1) * XSTRIDE + tid];   // x_dec(0)=x[:,T-1]
    __syncthreads();                                     // h(512) + xdec visible

    float* predbuf = (float*)xs;                         // 8 KB alias over dead xs
    const _Float16* xdp = xdec + (col >> 2) * 8;

    // ============ decoder: 64 steps (A0 -> A1 -> ...), fc + feedback ============
    for (int p = 0; p < Pp; ++p) {
        const _Float16* ar = (p & 1) ? arB : arA;
        _Float16*       hw = (p & 1) ? hwA : hwB;
        const _Float16* hb = (p & 1) ? A0  : A1;         // buffer written this step
        half8 ax = *(const half8*)(xdp);
        pgroup(ax, wx, biasv, PwA);                      // per-step x-contrib (P[.][0] valid)
        half8 a0 = *(const half8*)(ar);
        half8 a1 = *(const half8*)(ar + 32);
        float hn = qcell(a0, a1, w0, w1, PwA[2], PwA[0], PwA[1], PwA[3], cS);
        *hw = (_Float16)hn;
        __syncthreads();
        if (tid < MB * Ff) {
            int b = tid >> 3, f = tid & 7;
            const _Float16* hr = hb + (4 * b) * ROWS;
            float s = sfcb[f];
            #pragma unroll
            for (int ch = 0; ch < 8; ++ch) {
                half8 hh = *(const half8*)(hr + ch * 8);
                #pragma unroll
                for (int j = 0; j < 8; ++j)
                    s += (float)hh[j] * fcWT[(ch * 8 + j) * 9 + f];
            }
            predbuf[b * (Pp * Ff) + p * Ff + f] = s;
            xdec[tid] = (_Float16)s;
        }
        __syncthreads();
    }

    // ================= flush preds: LDS -> global, coalesced float4 =================
    {
        f32x4* out4 = (f32x4*)out + (size_t)b0 * (Pp * Ff / 4);
        const f32x4* pb4 = (const f32x4*)predbuf;
        for (int i = tid; i < MB * Pp * Ff / 4; i += 256)
            out4[i] = pb4[i];
    }
}

extern "C" void kernel_launch(void* const* d_in, const int* in_sizes, int n_in,
                              void* d_out, int out_size, void* d_ws, size_t ws_size,
                              hipStream_t stream) {
    (void)in_sizes; (void)n_in; (void)d_ws; (void)ws_size; (void)out_size;
    hipLaunchKernelGGL(seq2seq_v9, dim3(NBLK), dim3(256), 0, stream,
                       (const float*)d_in[0],
                       (const float*)d_in[1], (const float*)d_in[2],
                       (const float*)d_in[3], (const float*)d_in[4],
                       (const float*)d_in[5], (const float*)d_in[6],
                       (const float*)d_in[7], (const float*)d_in[8],
                       (const float*)d_in[9], (const float*)d_in[10],
                       (float*)d_out);
}